// Round 1
// baseline (1647.153 us; speedup 1.0000x reference)
//
#include <hip/hip_runtime.h>
#include <math.h>

// ---------------------------------------------------------------------------
// QCNN+QLSTM+QSampler fused forward.
//   out layout: [0,B)   qcnn  (B,1)
//               [B,11B) tag   (B,1,10)
//               [11B,15B) samp (B,4)
//   ws: B*16 floats of LSTM hidden states (outs), consumed by k_tag.
// ---------------------------------------------------------------------------

__device__ __forceinline__ float2 cmulf(float2 a, float2 b){
  return make_float2(a.x*b.x - a.y*b.y, a.x*b.y + a.y*b.x);
}
__device__ __forceinline__ float fast_tanh(float x){
  // 2*sigmoid(2x)-1; overflow-safe for both signs (exp->inf => -1, exp->0 => 1)
  return 2.0f/(1.0f + __expf(-2.0f*x)) - 1.0f;
}

// prefix-product helper: value of lane (row position - D) within 16-lane row,
// 1.0f when the source is out of the row (DPP row_shr keeps `old`).
template<int D>
__device__ __forceinline__ float row_shr_or_one(float v){
  return __int_as_float(__builtin_amdgcn_update_dpp(
      __float_as_int(1.0f), __float_as_int(v), 0x110 | D, 0xF, 0xF, false));
}

// ---------------- 8-qubit statevector: 64 lanes x 4 amplitudes -------------
// amp index i (8 bits), qubit q bit = (i >> (7-q)) & 1 ; lane = i>>2, r = i&3.
// qubits 0..5 -> lane bits 5..0 ; qubit 6 -> r bit1 ; qubit 7 -> r bit0.

__device__ __forceinline__ void apply_diag(float2 (&s)[4], int q, float2 d0, float2 d1){
  const int lane = threadIdx.x;
  #pragma unroll
  for (int r=0;r<4;r++){
    int bit = (q>=6) ? ((r >> (7-q)) & 1) : ((lane >> (5-q)) & 1);
    s[r] = cmulf(s[r], bit ? d1 : d0);
  }
}

__device__ __forceinline__ void apply_real(float2 (&s)[4], int q,
                                           float m00, float m01, float m10, float m11){
  const int lane = threadIdx.x;
  if (q >= 6){
    const int st = 1 << (7-q);            // 2 for q=6, 1 for q=7
    for (int base=0;base<4;base++){
      if (base & st) continue;
      float2 a = s[base], b2 = s[base+st];
      s[base]    = make_float2(fmaf(m00,a.x, m01*b2.x), fmaf(m00,a.y, m01*b2.y));
      s[base+st] = make_float2(fmaf(m10,a.x, m11*b2.x), fmaf(m10,a.y, m11*b2.y));
    }
  } else {
    const int mask = 1 << (5-q);
    const bool hi = (lane & mask) != 0;
    #pragma unroll
    for (int r=0;r<4;r++){
      float ox = __shfl_xor(s[r].x, mask);
      float oy = __shfl_xor(s[r].y, mask);
      float2 m = s[r];
      if (!hi) s[r] = make_float2(fmaf(m00,m.x, m01*ox), fmaf(m00,m.y, m01*oy));
      else     s[r] = make_float2(fmaf(m10,ox, m11*m.x), fmaf(m10,oy, m11*m.y));
    }
  }
}

__device__ __forceinline__ void cnot_g(float2 (&s)[4], int c, int t){
  const int lane = threadIdx.x;
  if (t >= 6){
    const int st = 1 << (7-t);
    for (int base=0;base<4;base++){
      if (base & st) continue;
      int cb = (c>=6) ? ((base >> (7-c)) & 1) : ((lane >> (5-c)) & 1);
      if (cb){ float2 tmp=s[base]; s[base]=s[base+st]; s[base+st]=tmp; }
    }
  } else {
    const int mask = 1 << (5-t);
    #pragma unroll
    for (int r=0;r<4;r++){
      float ox = __shfl_xor(s[r].x, mask);
      float oy = __shfl_xor(s[r].y, mask);
      int cb = (c>=6) ? ((r >> (7-c)) & 1) : ((lane >> (5-c)) & 1);
      if (cb) s[r] = make_float2(ox, oy);
    }
  }
}

__device__ void conv_g(float2 (&s)[4], int qa, int qb, const float* p){
  const float R = 0.70710678118654752f;
  apply_diag(s, qb, make_float2(R,R), make_float2(R,-R));      // rz(-pi/2)
  cnot_g(s, qb, qa);
  float sn, cs;
  __sincosf(0.5f*p[0], &sn, &cs);
  apply_diag(s, qa, make_float2(cs,-sn), make_float2(cs,sn));  // rz(p0)
  __sincosf(0.5f*p[1], &sn, &cs);
  apply_real(s, qb, cs, -sn, sn, cs);                          // ry(p1)
  cnot_g(s, qa, qb);
  __sincosf(0.5f*p[2], &sn, &cs);
  apply_real(s, qb, cs, -sn, sn, cs);                          // ry(p2)
  cnot_g(s, qb, qa);
  apply_diag(s, qa, make_float2(R,-R), make_float2(R,R));      // rz(pi/2)
}

__device__ void pool_g(float2 (&s)[4], int qa, int qb, const float* p){
  const float R = 0.70710678118654752f;
  apply_diag(s, qb, make_float2(R,R), make_float2(R,-R));      // rz(-pi/2)
  cnot_g(s, qb, qa);
  float sn, cs;
  __sincosf(0.5f*p[0], &sn, &cs);
  apply_diag(s, qa, make_float2(cs,-sn), make_float2(cs,sn));  // rz(p0)
  __sincosf(0.5f*p[1], &sn, &cs);
  apply_real(s, qb, cs, -sn, sn, cs);                          // ry(p1)
  cnot_g(s, qa, qb);
  __sincosf(0.5f*p[2], &sn, &cs);
  apply_real(s, qb, cs, -sn, sn, cs);                          // ry(p2)
}

// ---------------------------------------------------------------------------

extern "C" __global__ void __launch_bounds__(64)
k_fused(const float* __restrict__ inputs,
        const float* __restrict__ c1, const float* __restrict__ p1,
        const float* __restrict__ c2, const float* __restrict__ p2,
        const float* __restrict__ c3, const float* __restrict__ p3,
        const float* __restrict__ w_smp,
        const float* __restrict__ Wf, const float* __restrict__ bfv,
        const float* __restrict__ Wi, const float* __restrict__ biv,
        const float* __restrict__ Wu, const float* __restrict__ buv,
        const float* __restrict__ Wo, const float* __restrict__ bov,
        const float* __restrict__ thf, const float* __restrict__ thi,
        const float* __restrict__ thu, const float* __restrict__ tho,
        float* __restrict__ out, float* __restrict__ ws, int B)
{
  const int lane = threadIdx.x;
  __shared__ float hxs[16];

  if (blockIdx.x == 0){
    // ------------- sequential qLSTM scan over B steps (single wave) --------
    const int g = lane >> 4, e = lane & 15;   // gate (f,i,u,o), element
    const float* W  = (g==0)?Wf :(g==1)?Wi :(g==2)?Wu :Wo;
    const float* bb = (g==0)?bfv:(g==1)?biv:(g==2)?buv:bov;
    const float* th = (g==0)?thf:(g==1)?thi:(g==2)?thu:tho;
    float wx[8], wh[16];
    #pragma unroll
    for (int k=0;k<8;k++)  wx[k] = W[e*24+k];
    #pragma unroll
    for (int k=0;k<16;k++) wh[k] = W[e*24+8+k];
    const float bias  = bb[e];
    const float theta = th[e];
    if (lane < 16) hxs[lane] = 0.0f;
    float cx = 0.0f;
    float4 xa = *(const float4*)(inputs);
    float4 xb = *(const float4*)(inputs + 4);
    for (int t=0; t<B; t++){
      // prefetch next step's x (uniform address -> broadcast load)
      const int tn = (t+1 < B) ? (t+1) : t;
      float4 na = *(const float4*)(inputs + tn*8);
      float4 nb = *(const float4*)(inputs + tn*8 + 4);
      // hx broadcast via LDS (single wave: in-order DS pipe, no barrier needed)
      float4 h0 = *(const float4*)(&hxs[0]);
      float4 h1 = *(const float4*)(&hxs[4]);
      float4 h2 = *(const float4*)(&hxs[8]);
      float4 h3 = *(const float4*)(&hxs[12]);
      float a0 = bias, a1 = 0.f, a2 = 0.f, a3 = 0.f;
      a0 = fmaf(wx[0], xa.x, a0); a1 = fmaf(wx[1], xa.y, a1);
      a2 = fmaf(wx[2], xa.z, a2); a3 = fmaf(wx[3], xa.w, a3);
      a0 = fmaf(wx[4], xb.x, a0); a1 = fmaf(wx[5], xb.y, a1);
      a2 = fmaf(wx[6], xb.z, a2); a3 = fmaf(wx[7], xb.w, a3);
      a0 = fmaf(wh[0], h0.x, a0); a1 = fmaf(wh[1], h0.y, a1);
      a2 = fmaf(wh[2], h0.z, a2); a3 = fmaf(wh[3], h0.w, a3);
      a0 = fmaf(wh[4], h1.x, a0); a1 = fmaf(wh[5], h1.y, a1);
      a2 = fmaf(wh[6], h1.z, a2); a3 = fmaf(wh[7], h1.w, a3);
      a0 = fmaf(wh[8], h2.x, a0); a1 = fmaf(wh[9], h2.y, a1);
      a2 = fmaf(wh[10],h2.z, a2); a3 = fmaf(wh[11],h2.w, a3);
      a0 = fmaf(wh[12],h3.x, a0); a1 = fmaf(wh[13],h3.y, a1);
      a2 = fmaf(wh[14],h3.z, a2); a3 = fmaf(wh[15],h3.w, a3);
      const float acc = (a0+a1) + (a2+a3);
      // qlayer: c = cos(v+theta); out[0]=c1..c15, out[e>=1]=c0..ce
      const float c = __cosf(acc + theta);
      float pq = (e==0) ? 1.0f : c;            // c'_e with c'_0 := 1
      pq *= row_shr_or_one<1>(pq);
      pq *= row_shr_or_one<2>(pq);
      pq *= row_shr_or_one<4>(pq);
      pq *= row_shr_or_one<8>(pq);             // pq[e] = prod_{k=1..e} c_k
      const float c0  = __shfl(c, 0, 16);
      const float q15 = __shfl(pq, 15, 16);
      const float v = (e==0) ? q15 : c0 * pq;
      // activation: sigmoid for f,i,o; tanh for u (one exp for all lanes)
      const float xin = (g==2) ? 2.0f*v : v;
      const float sg  = 1.0f/(1.0f + __expf(-xin));
      const float act = (g==2) ? (2.0f*sg - 1.0f) : sg;
      // gather the four gate values for my element
      const float f  = __shfl(act, e);
      const float ii = __shfl(act, e+16);
      const float u  = __shfl(act, e+32);
      const float o  = __shfl(act, e+48);
      cx = fmaf(f, cx, ii*u);
      const float hx = o * fast_tanh(cx);
      if (lane < 16){ hxs[lane] = hx; ws[t*16 + lane] = hx; }
      xa = na; xb = nb;
    }
    return;
  }

  // ---------------- QCNN (one wave per sample) + sampler -------------------
  const int b = blockIdx.x - 1;
  float2 s[4];
  s[0] = make_float2(0.f,0.f); s[1]=s[0]; s[2]=s[0]; s[3]=s[0];
  if (lane == 0) s[0] = make_float2(1.f, 0.f);
  float xl[8];
  #pragma unroll
  for (int k=0;k<8;k++) xl[k] = inputs[b*8+k];
  const float R = 0.70710678118654752f;
  for (int rep=0;rep<2;rep++){
    for (int q=0;q<8;q++) apply_real(s, q, R, R, R, -R);       // H
    for (int q=0;q<8;q++){
      float sn, cs; __sincosf(2.0f*xl[q], &sn, &cs);
      apply_diag(s, q, make_float2(1.f,0.f), make_float2(cs,sn)); // phase(2x)
    }
  }
  for (int k=0;k<4;k++) conv_g(s, 2*k, 2*k+1, c1+3*k);
  for (int k=0;k<4;k++) pool_g(s, k, k+4, p1+3*k);
  for (int k=0;k<2;k++) conv_g(s, 2*k, 2*k+1, c2+3*k);
  for (int k=0;k<2;k++) pool_g(s, k, k+2, p2+3*k);
  conv_g(s, 0, 1, c3);
  pool_g(s, 0, 1, p3);
  // expZ on qubit 7 (r bit0)
  float v = (s[0].x*s[0].x + s[0].y*s[0].y) - (s[1].x*s[1].x + s[1].y*s[1].y)
          + (s[2].x*s[2].x + s[2].y*s[2].y) - (s[3].x*s[3].x + s[3].y*s[3].y);
  #pragma unroll
  for (int d=1; d<64; d<<=1) v += __shfl_xor(v, d);
  if (lane == 0){
    out[b] = v;
    // ---- 2-qubit real sampler ----
    float a00=1.f, a01=0.f, a10=0.f, a11=0.f;
    float sn, cs, t0, t1;
    #define RY0(T) { __sincosf(0.5f*(T), &sn, &cs); \
      t0 = cs*a00 - sn*a10; t1 = sn*a00 + cs*a10; a00=t0; a10=t1; \
      t0 = cs*a01 - sn*a11; t1 = sn*a01 + cs*a11; a01=t0; a11=t1; }
    #define RY1(T) { __sincosf(0.5f*(T), &sn, &cs); \
      t0 = cs*a00 - sn*a01; t1 = sn*a00 + cs*a01; a00=t0; a01=t1; \
      t0 = cs*a10 - sn*a11; t1 = sn*a10 + cs*a11; a10=t0; a11=t1; }
    #define CN01 { float tmp=a10; a10=a11; a11=tmp; }
    RY0(xl[0]); RY1(xl[1]); CN01;
    RY0(w_smp[0]); RY1(w_smp[1]); CN01;
    RY0(w_smp[2]); RY1(w_smp[3]);
    #undef RY0
    #undef RY1
    #undef CN01
    float* samp = out + B + B*10;
    samp[b*4+0] = a00*a00; samp[b*4+1] = a10*a10;
    samp[b*4+2] = a01*a01; samp[b*4+3] = a11*a11;
  }
}

// tag = log_softmax(outs @ Wt.T + bt), parallel over B
extern "C" __global__ void __launch_bounds__(256)
k_tag(const float* __restrict__ hs, const float* __restrict__ Wt,
      const float* __restrict__ bt, float* __restrict__ tag, int B)
{
  const int b = blockIdx.x*blockDim.x + threadIdx.x;
  if (b >= B) return;
  const float4* hp = (const float4*)(hs + b*16);
  const float4 h0=hp[0], h1=hp[1], h2=hp[2], h3=hp[3];
  float lg[10];
  #pragma unroll
  for (int j=0;j<10;j++){
    const float* w = Wt + j*16;
    float s0 = fmaf(w[0],h0.x, bt[j]); s0=fmaf(w[4],h1.x,s0); s0=fmaf(w[8],h2.x,s0);  s0=fmaf(w[12],h3.x,s0);
    float s1 = w[1]*h0.y;              s1=fmaf(w[5],h1.y,s1); s1=fmaf(w[9],h2.y,s1);  s1=fmaf(w[13],h3.y,s1);
    float s2 = w[2]*h0.z;              s2=fmaf(w[6],h1.z,s2); s2=fmaf(w[10],h2.z,s2); s2=fmaf(w[14],h3.z,s2);
    float s3 = w[3]*h0.w;              s3=fmaf(w[7],h1.w,s3); s3=fmaf(w[11],h2.w,s3); s3=fmaf(w[15],h3.w,s3);
    lg[j] = (s0+s1)+(s2+s3);
  }
  float m = lg[0];
  #pragma unroll
  for (int j=1;j<10;j++) m = fmaxf(m, lg[j]);
  float ss = 0.f;
  #pragma unroll
  for (int j=0;j<10;j++) ss += __expf(lg[j]-m);
  const float lse = __logf(ss) + m;
  #pragma unroll
  for (int j=0;j<10;j++) tag[b*10+j] = lg[j] - lse;
}

extern "C" void kernel_launch(void* const* d_in, const int* in_sizes, int n_in,
                              void* d_out, int out_size, void* d_ws, size_t ws_size,
                              hipStream_t stream)
{
  const float* inputs = (const float*)d_in[0];
  const float* c1  = (const float*)d_in[1];
  const float* p1  = (const float*)d_in[2];
  const float* c2  = (const float*)d_in[3];
  const float* p2  = (const float*)d_in[4];
  const float* c3  = (const float*)d_in[5];
  const float* p3  = (const float*)d_in[6];
  const float* wsm = (const float*)d_in[7];
  const float* Wf  = (const float*)d_in[8];
  const float* bf_ = (const float*)d_in[9];
  const float* Wi  = (const float*)d_in[10];
  const float* bi_ = (const float*)d_in[11];
  const float* Wu  = (const float*)d_in[12];
  const float* bu_ = (const float*)d_in[13];
  const float* Wo  = (const float*)d_in[14];
  const float* bo_ = (const float*)d_in[15];
  const float* thf = (const float*)d_in[16];
  const float* thi = (const float*)d_in[17];
  const float* thu = (const float*)d_in[18];
  const float* tho = (const float*)d_in[19];
  const float* Wt  = (const float*)d_in[20];
  const float* bt  = (const float*)d_in[21];
  const int B = in_sizes[0] / 8;          // 4096
  float* out = (float*)d_out;
  float* ws  = (float*)d_ws;              // needs B*16*4 = 256 KiB scratch

  k_fused<<<B+1, 64, 0, stream>>>(inputs, c1,p1,c2,p2,c3,p3, wsm,
                                  Wf,bf_,Wi,bi_,Wu,bu_,Wo,bo_,
                                  thf,thi,thu,tho, out, ws, B);
  k_tag<<<(B+255)/256, 256, 0, stream>>>(ws, Wt, bt, out + B, B);
}